// Round 5
// baseline (141.864 us; speedup 1.0000x reference)
//
#include <hip/hip_runtime.h>
#include <hip/hip_cooperative_groups.h>
#include <stdint.h>

namespace cg = cooperative_groups;

typedef __attribute__((ext_vector_type(8))) short short8;
typedef __attribute__((ext_vector_type(4))) float f32x4;
typedef __attribute__((ext_vector_type(4))) unsigned int u32x4;

#define NE 500000
#define NN 50000
#define NTILES 3125
#define NPAIRS 1563   // ceil(NTILES/2); pair 1562 has a phantom second tile
#define GRID_X 256
#define BLOCK_X 512

__device__ __forceinline__ unsigned int f2bf1(float f) {
  unsigned int u = __builtin_bit_cast(unsigned int, f);
  u += 0x7FFFu + ((u >> 16) & 1u);   // round-to-nearest-even
  return u >> 16;
}
__device__ __forceinline__ unsigned int packbf2(float lo, float hi) {
  return f2bf1(lo) | (f2bf1(hi) << 16);
}
__device__ __forceinline__ short8 pack8(f32x4 a, f32x4 b) {
  short8 r;
  r[0] = (short)f2bf1(a[0]); r[1] = (short)f2bf1(a[1]);
  r[2] = (short)f2bf1(a[2]); r[3] = (short)f2bf1(a[3]);
  r[4] = (short)f2bf1(b[0]); r[5] = (short)f2bf1(b[1]);
  r[6] = (short)f2bf1(b[2]); r[7] = (short)f2bf1(b[3]);
  return r;
}

// ---------------------------------------------------------------------------
// Single cooperative kernel: MLP phase -> grid sync -> scatter phase.
//   MLP: 8 waves/block, one tile-pair per wave (B=2 weight amortize), weights
//   repacked f32->bf16 MFMA fragments in LDS by each working block.
//   k-relabel trick keeps layer transitions entirely in registers.
//   Scatter: out[e] = R[edge_index[e,1]], 4 lanes/edge, NT stores.
// ---------------------------------------------------------------------------
__global__ __launch_bounds__(BLOCK_X, 2) void fused_kernel(
    const float* __restrict__ ef, const float* __restrict__ nfeat,
    const float* __restrict__ W1, const float* __restrict__ b1,
    const float* __restrict__ W2, const float* __restrict__ b2,
    const float* __restrict__ W3, const float* __restrict__ b3,
    const float* __restrict__ W4, const float* __restrict__ b4,
    float* __restrict__ Rout,
    const int* __restrict__ eidx, float* __restrict__ out) {
  __shared__ __align__(16) unsigned short wlds[69632];   // 136 KB: 136 frags x 512 u16
  __shared__ __align__(16) float blds[640];              // b1|b2|b3|b4

  const int t = threadIdx.x;
  const bool block_has_work = (blockIdx.x * 8 < NPAIRS);

  if (block_has_work) {
    // ---- staging: repack weights into fragment order (8704 lane-tasks)
    #pragma unroll
    for (int i = 0; i < 17; ++i) {
      int idx = t + i * 512;
      int f = idx >> 6, l = idx & 63;
      int c2 = l & 15, g = l >> 4;
      const float *pa, *pb;
      if (f < 8) {                       // W1: standard slot layout (K=32)
        const float* base = W1 + (f * 16 + c2) * 32 + g * 8;
        pa = base; pb = base + 4;
      } else {                           // W2/W3/W4: pi-relabeled (K=128)
        const float* W; int i2, kfq, nb;
        if (f < 40)      { W = W2; i2 = f - 8;  kfq = i2 >> 3; nb = i2 & 7;  }
        else if (f < 72) { W = W3; i2 = f - 40; kfq = i2 >> 3; nb = i2 & 7;  }
        else             { W = W4; i2 = f - 72; kfq = i2 >> 4; nb = i2 & 15; }
        const float* base = W + (nb * 16 + c2) * 128 + g * 4;
        pa = base + kfq * 16;            // j=0..3  -> k = kfq*16 + g*4 + j
        pb = base + (kfq + 4) * 16;      // j=4..7  -> k = (kfq+4)*16 + g*4 + (j-4)
      }
      f32x4 x0 = *(const f32x4*)pa;
      f32x4 x1 = *(const f32x4*)pb;
      *(short8*)&wlds[f * 512 + l * 8] = pack8(x0, x1);
    }
    if (t < 160) {
      const float* s = t < 32 ? b1 + t * 4
                     : t < 64 ? b2 + (t - 32) * 4
                     : t < 96 ? b3 + (t - 64) * 4
                     :          b4 + (t - 96) * 4;
      ((f32x4*)blds)[t] = *(const f32x4*)s;
    }
    __syncthreads();

    const int lane = t & 63, w = t >> 6;
    const int l15 = lane & 15, lg = lane >> 4;
    const int p = blockIdx.x * 8 + w;

    if (p < NPAIRS) {
      const int tA = 2 * p, tB = 2 * p + 1;
      const bool actB = (tB < NTILES);
      const int nA = tA * 16, nB = (actB ? tB : tA) * 16;

      // ReLU + pack C-layout acc into next-layer A-fragments (pure registers)
      auto transition = [&](const f32x4* a, short8* af) {
        unsigned int pk[8][2];
        #pragma unroll
        for (int nb = 0; nb < 8; ++nb) {
          pk[nb][0] = packbf2(fmaxf(a[nb][0], 0.f), fmaxf(a[nb][1], 0.f));
          pk[nb][1] = packbf2(fmaxf(a[nb][2], 0.f), fmaxf(a[nb][3], 0.f));
        }
        #pragma unroll
        for (int kf = 0; kf < 4; ++kf) {
          u32x4 u = { pk[kf][0], pk[kf][1], pk[kf + 4][0], pk[kf + 4][1] };
          af[kf] = __builtin_bit_cast(short8, u);
        }
      };

      // ---- layer 1: D = W1(A) x X^T(B), standard slots
      const float* xa = ef + (nA + l15) * 32 + lg * 8;
      const float* xb = ef + (nB + l15) * 32 + lg * 8;
      short8 a1A = pack8(*(const f32x4*)xa, *(const f32x4*)(xa + 4));
      short8 a1B = pack8(*(const f32x4*)xb, *(const f32x4*)(xb + 4));
      f32x4 accA[8], accB[8];
      #pragma unroll
      for (int nb = 0; nb < 8; ++nb) {
        f32x4 c0 = *(const f32x4*)&blds[nb * 16 + lg * 4];
        short8 wv = *(const short8*)&wlds[nb * 512 + lane * 8];
        accA[nb] = __builtin_amdgcn_mfma_f32_16x16x32_bf16(wv, a1A, c0, 0, 0, 0);
        accB[nb] = __builtin_amdgcn_mfma_f32_16x16x32_bf16(wv, a1B, c0, 0, 0, 0);
      }
      short8 afA[4], afB[4];
      transition(accA, afA);
      transition(accB, afB);

      // ---- layers 2 and 3 (pi-relabeled weights from LDS)
      #pragma unroll
      for (int L = 0; L < 2; ++L) {
        const int wbase = 8 + L * 32, bbase = 128 + L * 128;
        #pragma unroll
        for (int nb = 0; nb < 8; ++nb) {
          f32x4 c0 = *(const f32x4*)&blds[bbase + nb * 16 + lg * 4];
          f32x4 cA = c0, cB = c0;
          #pragma unroll
          for (int kf = 0; kf < 4; ++kf) {
            short8 wv = *(const short8*)&wlds[(wbase + kf * 8 + nb) * 512 + lane * 8];
            cA = __builtin_amdgcn_mfma_f32_16x16x32_bf16(wv, afA[kf], cA, 0, 0, 0);
            cB = __builtin_amdgcn_mfma_f32_16x16x32_bf16(wv, afB[kf], cB, 0, 0, 0);
          }
          accA[nb] = cA; accB[nb] = cB;
        }
        transition(accA, afA);
        transition(accB, afB);
      }

      // ---- layer 4 (pi-relabeled weights from LDS) + einsum epilogue
      f32x4 nfvA = *(const f32x4*)(nfeat + (nA + l15) * 16 + lg * 4);
      f32x4 nfvB = *(const f32x4*)(nfeat + (nB + l15) * 16 + lg * 4);
      float oA0 = 0.f, oA1 = 0.f, oA2 = 0.f, oA3 = 0.f;
      float oB0 = 0.f, oB1 = 0.f, oB2 = 0.f, oB3 = 0.f;
      #pragma unroll
      for (int nb = 0; nb < 16; ++nb) {
        f32x4 c0 = *(const f32x4*)&blds[384 + nb * 16 + lg * 4];
        f32x4 dA = c0, dB = c0;
        #pragma unroll
        for (int kf = 0; kf < 4; ++kf) {
          short8 wv = *(const short8*)&wlds[(72 + kf * 16 + nb) * 512 + lane * 8];
          dA = __builtin_amdgcn_mfma_f32_16x16x32_bf16(wv, afA[kf], dA, 0, 0, 0);
          dB = __builtin_amdgcn_mfma_f32_16x16x32_bf16(wv, afB[kf], dB, 0, 0, 0);
        }
        // lane holds H4[m=l15][c=nb*16+lg*4+r]; j = lg*4+r, i = nb
        float pA = dA[0]*nfvA[0] + dA[1]*nfvA[1] + dA[2]*nfvA[2] + dA[3]*nfvA[3];
        float pB = dB[0]*nfvB[0] + dB[1]*nfvB[1] + dB[2]*nfvB[2] + dB[3]*nfvB[3];
        pA += __shfl_xor(pA, 16, 64); pA += __shfl_xor(pA, 32, 64);
        pB += __shfl_xor(pB, 16, 64); pB += __shfl_xor(pB, 32, 64);
        int rs = nb - lg * 4;
        oA0 = (rs == 0) ? pA : oA0; oA1 = (rs == 1) ? pA : oA1;
        oA2 = (rs == 2) ? pA : oA2; oA3 = (rs == 3) ? pA : oA3;
        oB0 = (rs == 0) ? pB : oB0; oB1 = (rs == 1) ? pB : oB1;
        oB2 = (rs == 2) ? pB : oB2; oB3 = (rs == 3) ? pB : oB3;
      }
      f32x4 oA = { oA0, oA1, oA2, oA3 };
      *(f32x4*)(Rout + (nA + l15) * 16 + lg * 4) = oA;
      if (actB) {
        f32x4 oB = { oB0, oB1, oB2, oB3 };
        *(f32x4*)(Rout + (nB + l15) * 16 + lg * 4) = oB;
      }
    }
  }

  // ---- make Rout visible device-wide, then barrier
  __threadfence();
  cg::this_grid().sync();

  // ---- scatter phase: out[e] = R[eidx[e,1]]; 4 lanes/edge, 16B/lane
  {
    const int total = NE * 4;
    const int stride = GRID_X * BLOCK_X;
    int tid = blockIdx.x * BLOCK_X + t;
    #pragma unroll 2
    for (; tid < total; tid += stride) {
      int e = tid >> 2, pp = tid & 3;
      int nb = eidx[2 * e + 1];
      f32x4 v = *(const f32x4*)(Rout + nb * 16 + pp * 4);
      __builtin_nontemporal_store(v, (f32x4*)(out + e * 16 + pp * 4));
    }
  }
}

extern "C" void kernel_launch(void* const* d_in, const int* in_sizes, int n_in,
                              void* d_out, int out_size, void* d_ws, size_t ws_size,
                              hipStream_t stream) {
  const float* ef = (const float*)d_in[0];
  const float* nf = (const float*)d_in[1];
  const float* W1 = (const float*)d_in[2];
  const float* b1 = (const float*)d_in[3];
  const float* W2 = (const float*)d_in[4];
  const float* b2 = (const float*)d_in[5];
  const float* W3 = (const float*)d_in[6];
  const float* b3 = (const float*)d_in[7];
  const float* W4 = (const float*)d_in[8];
  const float* b4 = (const float*)d_in[9];
  const int* eidx = (const int*)d_in[10];

  float* Rbuf = (float*)d_ws;                 // NN*16 f32 = 3.2 MB
  float* out = (float*)d_out;

  void* args[] = { (void*)&ef, (void*)&nf, (void*)&W1, (void*)&b1,
                   (void*)&W2, (void*)&b2, (void*)&W3, (void*)&b3,
                   (void*)&W4, (void*)&b4, (void*)&Rbuf,
                   (void*)&eidx, (void*)&out };
  hipLaunchCooperativeKernel((void*)fused_kernel, dim3(GRID_X), dim3(BLOCK_X),
                             args, 0, stream);
}

// Round 6
// 48.750 us; speedup vs baseline: 2.9100x; 2.9100x over previous
//
#include <hip/hip_runtime.h>
#include <stdint.h>

typedef __attribute__((ext_vector_type(8))) short short8;
typedef __attribute__((ext_vector_type(4))) float f32x4;
typedef __attribute__((ext_vector_type(4))) unsigned int u32x4;

#define NE 500000
#define NN 50000
#define NTILES 3125
#define NPAIRS 1563      // ceil(NTILES/2); pair 1562 has a phantom second tile
#define MLP_BLOCKS 98    // ceil(NPAIRS/16)
#define SC_BLOCKS 2048
#define SC_THREADS (SC_BLOCKS * 256)

__device__ __forceinline__ unsigned int f2bf1(float f) {
  unsigned int u = __builtin_bit_cast(unsigned int, f);
  u += 0x7FFFu + ((u >> 16) & 1u);   // round-to-nearest-even
  return u >> 16;
}
__device__ __forceinline__ unsigned int packbf2(float lo, float hi) {
  return f2bf1(lo) | (f2bf1(hi) << 16);
}
__device__ __forceinline__ short8 pack8(f32x4 a, f32x4 b) {
  short8 r;
  r[0] = (short)f2bf1(a[0]); r[1] = (short)f2bf1(a[1]);
  r[2] = (short)f2bf1(a[2]); r[3] = (short)f2bf1(a[3]);
  r[4] = (short)f2bf1(b[0]); r[5] = (short)f2bf1(b[1]);
  r[6] = (short)f2bf1(b[2]); r[7] = (short)f2bf1(b[3]);
  return r;
}

// ---------------------------------------------------------------------------
// MLP kernel: 1024 threads = 16 waves/block, one tile-pair per wave (B=2).
// 1 block/CU (136 KB LDS) -> 4 waves/SIMD. Each block repacks W1..W4
// (f32, global/LLC) into bf16 MFMA fragments in LDS. k-relabel trick keeps
// all layer transitions in registers (no LDS scratch, no drains).
// ---------------------------------------------------------------------------
__global__ __launch_bounds__(1024, 4) void mlp_kernel(
    const float* __restrict__ ef, const float* __restrict__ nfeat,
    const float* __restrict__ W1, const float* __restrict__ b1,
    const float* __restrict__ W2, const float* __restrict__ b2,
    const float* __restrict__ W3, const float* __restrict__ b3,
    const float* __restrict__ W4, const float* __restrict__ b4,
    float* __restrict__ Rout) {
  __shared__ __align__(16) unsigned short wlds[69632];   // 136 KB: 136 frags x 512 u16
  __shared__ __align__(16) float blds[640];              // b1|b2|b3|b4

  const int t = threadIdx.x;
  // ---- staging: repack weights into fragment order (8704 lane-tasks)
  #pragma unroll
  for (int i = 0; i < 9; ++i) {
    int idx = t + i * 1024;
    if (idx < 8704) {
      int f = idx >> 6, l = idx & 63;
      int c2 = l & 15, g = l >> 4;
      const float *pa, *pb;
      if (f < 8) {                       // W1: standard slot layout (K=32)
        const float* base = W1 + (f * 16 + c2) * 32 + g * 8;
        pa = base; pb = base + 4;
      } else {                           // W2/W3/W4: pi-relabeled (K=128)
        const float* W; int i2, kfq, nb;
        if (f < 40)      { W = W2; i2 = f - 8;  kfq = i2 >> 3; nb = i2 & 7;  }
        else if (f < 72) { W = W3; i2 = f - 40; kfq = i2 >> 3; nb = i2 & 7;  }
        else             { W = W4; i2 = f - 72; kfq = i2 >> 4; nb = i2 & 15; }
        const float* base = W + (nb * 16 + c2) * 128 + g * 4;
        pa = base + kfq * 16;            // j=0..3  -> k = kfq*16 + g*4 + j
        pb = base + (kfq + 4) * 16;      // j=4..7  -> k = (kfq+4)*16 + g*4 + (j-4)
      }
      f32x4 x0 = *(const f32x4*)pa;
      f32x4 x1 = *(const f32x4*)pb;
      *(short8*)&wlds[f * 512 + l * 8] = pack8(x0, x1);
    }
  }
  if (t < 160) {
    const float* s = t < 32 ? b1 + t * 4
                   : t < 64 ? b2 + (t - 32) * 4
                   : t < 96 ? b3 + (t - 64) * 4
                   :          b4 + (t - 96) * 4;
    ((f32x4*)blds)[t] = *(const f32x4*)s;
  }
  __syncthreads();

  const int lane = t & 63, w = t >> 6;
  const int l15 = lane & 15, lg = lane >> 4;

  const int p = blockIdx.x * 16 + w;
  if (p >= NPAIRS) return;
  const int tA = 2 * p, tB = 2 * p + 1;
  const bool actB = (tB < NTILES);
  const int nA = tA * 16, nB = (actB ? tB : tA) * 16;

  // ReLU + pack C-layout acc into next-layer A-fragments (pure registers)
  auto transition = [&](const f32x4* a, short8* af) {
    unsigned int pk[8][2];
    #pragma unroll
    for (int nb = 0; nb < 8; ++nb) {
      pk[nb][0] = packbf2(fmaxf(a[nb][0], 0.f), fmaxf(a[nb][1], 0.f));
      pk[nb][1] = packbf2(fmaxf(a[nb][2], 0.f), fmaxf(a[nb][3], 0.f));
    }
    #pragma unroll
    for (int kf = 0; kf < 4; ++kf) {
      u32x4 u = { pk[kf][0], pk[kf][1], pk[kf + 4][0], pk[kf + 4][1] };
      af[kf] = __builtin_bit_cast(short8, u);
    }
  };

  // ---- layer 1: D = W1(A) x X^T(B), standard slots
  const float* xa = ef + (nA + l15) * 32 + lg * 8;
  const float* xb = ef + (nB + l15) * 32 + lg * 8;
  short8 a1A = pack8(*(const f32x4*)xa, *(const f32x4*)(xa + 4));
  short8 a1B = pack8(*(const f32x4*)xb, *(const f32x4*)(xb + 4));
  f32x4 accA[8], accB[8];
  #pragma unroll
  for (int nb = 0; nb < 8; ++nb) {
    f32x4 c0 = *(const f32x4*)&blds[nb * 16 + lg * 4];
    short8 wv = *(const short8*)&wlds[nb * 512 + lane * 8];
    accA[nb] = __builtin_amdgcn_mfma_f32_16x16x32_bf16(wv, a1A, c0, 0, 0, 0);
    accB[nb] = __builtin_amdgcn_mfma_f32_16x16x32_bf16(wv, a1B, c0, 0, 0, 0);
  }
  short8 afA[4], afB[4];
  transition(accA, afA);
  transition(accB, afB);

  // ---- layers 2 and 3 (pi-relabeled weights from LDS)
  #pragma unroll
  for (int L = 0; L < 2; ++L) {
    const int wbase = 8 + L * 32, bbase = 128 + L * 128;
    #pragma unroll
    for (int nb = 0; nb < 8; ++nb) {
      f32x4 c0 = *(const f32x4*)&blds[bbase + nb * 16 + lg * 4];
      f32x4 cA = c0, cB = c0;
      #pragma unroll
      for (int kf = 0; kf < 4; ++kf) {
        short8 wv = *(const short8*)&wlds[(wbase + kf * 8 + nb) * 512 + lane * 8];
        cA = __builtin_amdgcn_mfma_f32_16x16x32_bf16(wv, afA[kf], cA, 0, 0, 0);
        cB = __builtin_amdgcn_mfma_f32_16x16x32_bf16(wv, afB[kf], cB, 0, 0, 0);
      }
      accA[nb] = cA; accB[nb] = cB;
    }
    transition(accA, afA);
    transition(accB, afB);
  }

  // ---- layer 4 (pi-relabeled weights from LDS) + einsum epilogue
  f32x4 nfvA = *(const f32x4*)(nfeat + (nA + l15) * 16 + lg * 4);
  f32x4 nfvB = *(const f32x4*)(nfeat + (nB + l15) * 16 + lg * 4);
  float oA0 = 0.f, oA1 = 0.f, oA2 = 0.f, oA3 = 0.f;
  float oB0 = 0.f, oB1 = 0.f, oB2 = 0.f, oB3 = 0.f;
  #pragma unroll
  for (int nb = 0; nb < 16; ++nb) {
    f32x4 c0 = *(const f32x4*)&blds[384 + nb * 16 + lg * 4];
    f32x4 dA = c0, dB = c0;
    #pragma unroll
    for (int kf = 0; kf < 4; ++kf) {
      short8 wv = *(const short8*)&wlds[(72 + kf * 16 + nb) * 512 + lane * 8];
      dA = __builtin_amdgcn_mfma_f32_16x16x32_bf16(wv, afA[kf], dA, 0, 0, 0);
      dB = __builtin_amdgcn_mfma_f32_16x16x32_bf16(wv, afB[kf], dB, 0, 0, 0);
    }
    // lane holds H4[m=l15][c=nb*16+lg*4+r]; j = lg*4+r, i = nb
    float pA = dA[0]*nfvA[0] + dA[1]*nfvA[1] + dA[2]*nfvA[2] + dA[3]*nfvA[3];
    float pB = dB[0]*nfvB[0] + dB[1]*nfvB[1] + dB[2]*nfvB[2] + dB[3]*nfvB[3];
    pA += __shfl_xor(pA, 16, 64); pA += __shfl_xor(pA, 32, 64);
    pB += __shfl_xor(pB, 16, 64); pB += __shfl_xor(pB, 32, 64);
    int rs = nb - lg * 4;
    oA0 = (rs == 0) ? pA : oA0; oA1 = (rs == 1) ? pA : oA1;
    oA2 = (rs == 2) ? pA : oA2; oA3 = (rs == 3) ? pA : oA3;
    oB0 = (rs == 0) ? pB : oB0; oB1 = (rs == 1) ? pB : oB1;
    oB2 = (rs == 2) ? pB : oB2; oB3 = (rs == 3) ? pB : oB3;
  }
  f32x4 oA = { oA0, oA1, oA2, oA3 };
  *(f32x4*)(Rout + (nA + l15) * 16 + lg * 4) = oA;
  if (actB) {
    f32x4 oB = { oB0, oB1, oB2, oB3 };
    *(f32x4*)(Rout + (nB + l15) * 16 + lg * 4) = oB;
  }
}

// ---------------------------------------------------------------------------
// Scatter: out[e] = R[edge_index[e,1]]. 4 lanes/edge, 16B/lane, PLAIN stores.
// Each thread handles 4 independent (edge,quarter) items, batched:
// 4 index loads -> 4 gathers -> 4 stores (max memory-level parallelism).
// Item i: out + i*4 <- R + nb(i)*16 + (i&3)*4.
// ---------------------------------------------------------------------------
__global__ __launch_bounds__(256) void scatter_kernel(
    const int* __restrict__ eidx, const float* __restrict__ Rbuf,
    float* __restrict__ out) {
  const int tid = blockIdx.x * 256 + threadIdx.x;
  const int total = NE * 4;
  const int i0 = tid;
  const int i1 = tid + SC_THREADS;
  const int i2 = tid + 2 * SC_THREADS;
  const int i3 = tid + 3 * SC_THREADS;
  const bool d3 = (i3 < total);          // i0..i2 always valid

  int nA = eidx[((i0 >> 2) << 1) + 1];
  int nB = eidx[((i1 >> 2) << 1) + 1];
  int nC = eidx[((i2 >> 2) << 1) + 1];
  int nD = d3 ? eidx[((i3 >> 2) << 1) + 1] : 0;

  f32x4 vA = *(const f32x4*)(Rbuf + nA * 16 + (i0 & 3) * 4);
  f32x4 vB = *(const f32x4*)(Rbuf + nB * 16 + (i1 & 3) * 4);
  f32x4 vC = *(const f32x4*)(Rbuf + nC * 16 + (i2 & 3) * 4);
  f32x4 vD = d3 ? *(const f32x4*)(Rbuf + nD * 16 + (i3 & 3) * 4) : f32x4{0,0,0,0};

  *(f32x4*)(out + (size_t)i0 * 4) = vA;
  *(f32x4*)(out + (size_t)i1 * 4) = vB;
  *(f32x4*)(out + (size_t)i2 * 4) = vC;
  if (d3) *(f32x4*)(out + (size_t)i3 * 4) = vD;
}

extern "C" void kernel_launch(void* const* d_in, const int* in_sizes, int n_in,
                              void* d_out, int out_size, void* d_ws, size_t ws_size,
                              hipStream_t stream) {
  const float* ef = (const float*)d_in[0];
  const float* nf = (const float*)d_in[1];
  const float* W1 = (const float*)d_in[2];
  const float* b1 = (const float*)d_in[3];
  const float* W2 = (const float*)d_in[4];
  const float* b2 = (const float*)d_in[5];
  const float* W3 = (const float*)d_in[6];
  const float* b3 = (const float*)d_in[7];
  const float* W4 = (const float*)d_in[8];
  const float* b4 = (const float*)d_in[9];
  const int* eidx = (const int*)d_in[10];

  float* Rbuf = (float*)d_ws;                 // NN*16 f32 = 3.2 MB
  float* out = (float*)d_out;

  hipLaunchKernelGGL(mlp_kernel, dim3(MLP_BLOCKS), dim3(1024), 0, stream,
                     ef, nf, W1, b1, W2, b2, W3, b3, W4, b4, Rbuf);
  hipLaunchKernelGGL(scatter_kernel, dim3(SC_BLOCKS), dim3(256), 0, stream,
                     eidx, Rbuf, out);
}

// Round 7
// 36.941 us; speedup vs baseline: 3.8402x; 1.3196x over previous
//
#include <hip/hip_runtime.h>
#include <stdint.h>

typedef __attribute__((ext_vector_type(8))) short short8;
typedef __attribute__((ext_vector_type(4))) float f32x4;
typedef __attribute__((ext_vector_type(4))) unsigned int u32x4;

#define NE 500000
#define NN 50000
#define NTILES 3125
#define WSLOTS 2048          // 256 blocks x 8 waves
#define SC_BLOCKS 2048
#define SC_THREADS (SC_BLOCKS * 256)

__device__ __forceinline__ unsigned int f2bf1(float f) {
  unsigned int u = __builtin_bit_cast(unsigned int, f);
  u += 0x7FFFu + ((u >> 16) & 1u);   // round-to-nearest-even
  return u >> 16;
}
__device__ __forceinline__ unsigned int packbf2(float lo, float hi) {
  return f2bf1(lo) | (f2bf1(hi) << 16);
}
__device__ __forceinline__ short8 pack8(f32x4 a, f32x4 b) {
  short8 r;
  r[0] = (short)f2bf1(a[0]); r[1] = (short)f2bf1(a[1]);
  r[2] = (short)f2bf1(a[2]); r[3] = (short)f2bf1(a[3]);
  r[4] = (short)f2bf1(b[0]); r[5] = (short)f2bf1(b[1]);
  r[6] = (short)f2bf1(b[2]); r[7] = (short)f2bf1(b[3]);
  return r;
}

// ---------------------------------------------------------------------------
// Prep: repack W1..W4 (f32) into bf16 MFMA fragments (pi-relabeled for K=128
// layers so inter-layer transitions stay in registers).
// Fragment f, lane l: frags [0,8)=W1 std, [8,40)=W2, [40,72)=W3, [72,136)=W4.
// ---------------------------------------------------------------------------
__global__ __launch_bounds__(256) void prep_weights(
    const float* __restrict__ W1, const float* __restrict__ W2,
    const float* __restrict__ W3, const float* __restrict__ W4,
    unsigned short* __restrict__ wf) {
  int idx = blockIdx.x * 256 + threadIdx.x;
  if (idx >= 8704) return;
  int f = idx >> 6, l = idx & 63;
  int c2 = l & 15, g = l >> 4;
  const float *pa, *pb;
  if (f < 8) {                       // W1: standard slot layout (K=32)
    const float* base = W1 + (f * 16 + c2) * 32 + g * 8;
    pa = base; pb = base + 4;
  } else {                           // W2/W3/W4: pi-relabeled (K=128)
    const float* W; int i2, kfq, nb;
    if (f < 40)      { W = W2; i2 = f - 8;  kfq = i2 >> 3; nb = i2 & 7;  }
    else if (f < 72) { W = W3; i2 = f - 40; kfq = i2 >> 3; nb = i2 & 7;  }
    else             { W = W4; i2 = f - 72; kfq = i2 >> 4; nb = i2 & 15; }
    const float* base = W + (nb * 16 + c2) * 128 + g * 4;
    pa = base + kfq * 16;            // j=0..3  -> k = kfq*16 + g*4 + j
    pb = base + (kfq + 4) * 16;      // j=4..7  -> k = (kfq+4)*16 + g*4 + (j-4)
  }
  f32x4 x0 = *(const f32x4*)pa;
  f32x4 x1 = *(const f32x4*)pb;
  *(short8*)&wf[f * 512 + l * 8] = pack8(x0, x1);
}

// ---------------------------------------------------------------------------
// MLP: 512 threads = 8 waves/block, 256 blocks (ALL CUs). Wave-slot
// g = w*256 + bid handles tile g (always) and tile g+2048 (if < NTILES) --
// the doubled waves land on waves 0..4 of EVERY block (uniform load).
// Weights: straight 139 KB vector copy of pre-packed frags into LDS.
// (512,2): 256-VGPR budget -> no spill (R6's (1024,4) spilled ~18 MB).
// k-relabel keeps all layer transitions in registers.
// ---------------------------------------------------------------------------
__global__ __launch_bounds__(512, 2) void mlp_kernel(
    const float* __restrict__ ef, const float* __restrict__ nfeat,
    const float* __restrict__ b1, const float* __restrict__ b2,
    const float* __restrict__ b3, const float* __restrict__ b4,
    const unsigned short* __restrict__ wf, float* __restrict__ Rout) {
  __shared__ __align__(16) unsigned short wlds[69632];   // 136 KB frags
  __shared__ __align__(16) float blds[640];              // b1|b2|b3|b4

  const int t = threadIdx.x;
  {
    const u32x4* src = (const u32x4*)wf;
    u32x4* dst = (u32x4*)wlds;
    #pragma unroll
    for (int i = 0; i < 17; ++i) dst[t + i * 512] = src[t + i * 512];
  }
  if (t < 160) {
    const float* s = t < 32 ? b1 + t * 4
                   : t < 64 ? b2 + (t - 32) * 4
                   : t < 96 ? b3 + (t - 64) * 4
                   :          b4 + (t - 96) * 4;
    ((f32x4*)blds)[t] = *(const f32x4*)s;
  }
  __syncthreads();

  const int lane = t & 63, w = t >> 6;
  const int l15 = lane & 15, lg = lane >> 4;

  const int g = w * 256 + blockIdx.x;      // 0..2047, tA=g always < NTILES
  const int tA = g;
  const bool actB = (g + WSLOTS < NTILES); // 1077 waves carry a second tile
  const int tB = actB ? g + WSLOTS : g;
  const int nA = tA * 16, nB = tB * 16;

  // ReLU + pack C-layout acc into next-layer A-fragments (pure registers)
  auto transition = [&](const f32x4* a, short8* af) {
    unsigned int pk[8][2];
    #pragma unroll
    for (int nb = 0; nb < 8; ++nb) {
      pk[nb][0] = packbf2(fmaxf(a[nb][0], 0.f), fmaxf(a[nb][1], 0.f));
      pk[nb][1] = packbf2(fmaxf(a[nb][2], 0.f), fmaxf(a[nb][3], 0.f));
    }
    #pragma unroll
    for (int kf = 0; kf < 4; ++kf) {
      u32x4 u = { pk[kf][0], pk[kf][1], pk[kf + 4][0], pk[kf + 4][1] };
      af[kf] = __builtin_bit_cast(short8, u);
    }
  };

  // ---- layer 1: D = W1(A) x X^T(B), standard slots
  const float* xa = ef + (nA + l15) * 32 + lg * 8;
  const float* xb = ef + (nB + l15) * 32 + lg * 8;
  short8 a1A = pack8(*(const f32x4*)xa, *(const f32x4*)(xa + 4));
  short8 a1B = pack8(*(const f32x4*)xb, *(const f32x4*)(xb + 4));
  f32x4 accA[8], accB[8];
  #pragma unroll
  for (int nb = 0; nb < 8; ++nb) {
    f32x4 c0 = *(const f32x4*)&blds[nb * 16 + lg * 4];
    short8 wv = *(const short8*)&wlds[nb * 512 + lane * 8];
    accA[nb] = __builtin_amdgcn_mfma_f32_16x16x32_bf16(wv, a1A, c0, 0, 0, 0);
    accB[nb] = __builtin_amdgcn_mfma_f32_16x16x32_bf16(wv, a1B, c0, 0, 0, 0);
  }
  short8 afA[4], afB[4];
  transition(accA, afA);
  transition(accB, afB);

  // ---- layers 2 and 3 (pi-relabeled weights from LDS)
  #pragma unroll
  for (int L = 0; L < 2; ++L) {
    const int wbase = 8 + L * 32, bbase = 128 + L * 128;
    #pragma unroll
    for (int nb = 0; nb < 8; ++nb) {
      f32x4 c0 = *(const f32x4*)&blds[bbase + nb * 16 + lg * 4];
      f32x4 cA = c0, cB = c0;
      #pragma unroll
      for (int kf = 0; kf < 4; ++kf) {
        short8 wv = *(const short8*)&wlds[(wbase + kf * 8 + nb) * 512 + lane * 8];
        cA = __builtin_amdgcn_mfma_f32_16x16x32_bf16(wv, afA[kf], cA, 0, 0, 0);
        cB = __builtin_amdgcn_mfma_f32_16x16x32_bf16(wv, afB[kf], cB, 0, 0, 0);
      }
      accA[nb] = cA; accB[nb] = cB;
    }
    transition(accA, afA);
    transition(accB, afB);
  }

  // ---- layer 4 (pi-relabeled weights from LDS) + einsum epilogue
  f32x4 nfvA = *(const f32x4*)(nfeat + (nA + l15) * 16 + lg * 4);
  f32x4 nfvB = *(const f32x4*)(nfeat + (nB + l15) * 16 + lg * 4);
  float oA0 = 0.f, oA1 = 0.f, oA2 = 0.f, oA3 = 0.f;
  float oB0 = 0.f, oB1 = 0.f, oB2 = 0.f, oB3 = 0.f;
  #pragma unroll
  for (int nb = 0; nb < 16; ++nb) {
    f32x4 c0 = *(const f32x4*)&blds[384 + nb * 16 + lg * 4];
    f32x4 dA = c0, dB = c0;
    #pragma unroll
    for (int kf = 0; kf < 4; ++kf) {
      short8 wv = *(const short8*)&wlds[(72 + kf * 16 + nb) * 512 + lane * 8];
      dA = __builtin_amdgcn_mfma_f32_16x16x32_bf16(wv, afA[kf], dA, 0, 0, 0);
      dB = __builtin_amdgcn_mfma_f32_16x16x32_bf16(wv, afB[kf], dB, 0, 0, 0);
    }
    // lane holds H4[m=l15][c=nb*16+lg*4+r]; j = lg*4+r, i = nb
    float pA = dA[0]*nfvA[0] + dA[1]*nfvA[1] + dA[2]*nfvA[2] + dA[3]*nfvA[3];
    float pB = dB[0]*nfvB[0] + dB[1]*nfvB[1] + dB[2]*nfvB[2] + dB[3]*nfvB[3];
    pA += __shfl_xor(pA, 16, 64); pA += __shfl_xor(pA, 32, 64);
    pB += __shfl_xor(pB, 16, 64); pB += __shfl_xor(pB, 32, 64);
    int rs = nb - lg * 4;
    oA0 = (rs == 0) ? pA : oA0; oA1 = (rs == 1) ? pA : oA1;
    oA2 = (rs == 2) ? pA : oA2; oA3 = (rs == 3) ? pA : oA3;
    oB0 = (rs == 0) ? pB : oB0; oB1 = (rs == 1) ? pB : oB1;
    oB2 = (rs == 2) ? pB : oB2; oB3 = (rs == 3) ? pB : oB3;
  }
  f32x4 oA = { oA0, oA1, oA2, oA3 };
  *(f32x4*)(Rout + (nA + l15) * 16 + lg * 4) = oA;
  if (actB) {
    f32x4 oB = { oB0, oB1, oB2, oB3 };
    *(f32x4*)(Rout + (nB + l15) * 16 + lg * 4) = oB;
  }
}

// ---------------------------------------------------------------------------
// Scatter: out[e] = R[edge_index[e,1]]. 4 lanes/edge, 16B/lane, plain stores,
// 4 independent items per thread for memory-level parallelism (R6-proven).
// ---------------------------------------------------------------------------
__global__ __launch_bounds__(256) void scatter_kernel(
    const int* __restrict__ eidx, const float* __restrict__ Rbuf,
    float* __restrict__ out) {
  const int tid = blockIdx.x * 256 + threadIdx.x;
  const int total = NE * 4;
  const int i0 = tid;
  const int i1 = tid + SC_THREADS;
  const int i2 = tid + 2 * SC_THREADS;
  const int i3 = tid + 3 * SC_THREADS;
  const bool d3 = (i3 < total);          // i0..i2 always valid

  int nA = eidx[((i0 >> 2) << 1) + 1];
  int nB = eidx[((i1 >> 2) << 1) + 1];
  int nC = eidx[((i2 >> 2) << 1) + 1];
  int nD = d3 ? eidx[((i3 >> 2) << 1) + 1] : 0;

  f32x4 vA = *(const f32x4*)(Rbuf + nA * 16 + (i0 & 3) * 4);
  f32x4 vB = *(const f32x4*)(Rbuf + nB * 16 + (i1 & 3) * 4);
  f32x4 vC = *(const f32x4*)(Rbuf + nC * 16 + (i2 & 3) * 4);
  f32x4 vD = d3 ? *(const f32x4*)(Rbuf + nD * 16 + (i3 & 3) * 4) : f32x4{0,0,0,0};

  *(f32x4*)(out + (size_t)i0 * 4) = vA;
  *(f32x4*)(out + (size_t)i1 * 4) = vB;
  *(f32x4*)(out + (size_t)i2 * 4) = vC;
  if (d3) *(f32x4*)(out + (size_t)i3 * 4) = vD;
}

extern "C" void kernel_launch(void* const* d_in, const int* in_sizes, int n_in,
                              void* d_out, int out_size, void* d_ws, size_t ws_size,
                              hipStream_t stream) {
  const float* ef = (const float*)d_in[0];
  const float* nf = (const float*)d_in[1];
  const float* W1 = (const float*)d_in[2];
  const float* b1 = (const float*)d_in[3];
  const float* W2 = (const float*)d_in[4];
  const float* b2 = (const float*)d_in[5];
  const float* W3 = (const float*)d_in[6];
  const float* b3 = (const float*)d_in[7];
  const float* W4 = (const float*)d_in[8];
  const float* b4 = (const float*)d_in[9];
  const int* eidx = (const int*)d_in[10];

  unsigned short* wfrag = (unsigned short*)d_ws;          // 139264 B bf16 frags
  float* Rbuf = (float*)((char*)d_ws + 139264);           // NN*16 f32 = 3.2 MB
  float* out = (float*)d_out;

  hipLaunchKernelGGL(prep_weights, dim3(34), dim3(256), 0, stream,
                     W1, W2, W3, W4, wfrag);
  hipLaunchKernelGGL(mlp_kernel, dim3(256), dim3(512), 0, stream,
                     ef, nf, b1, b2, b3, b4, wfrag, Rbuf);
  hipLaunchKernelGGL(scatter_kernel, dim3(SC_BLOCKS), dim3(256), 0, stream,
                     eidx, Rbuf, out);
}